// Round 2
// baseline (120.359 us; speedup 1.0000x reference)
//
#include <hip/hip_runtime.h>

#define BB 16
#define SS 2048
#define DD 64
#define OO 128
#define YEL (OO * DD)   // 8192 elems of Y[b]

typedef __attribute__((ext_vector_type(8))) short short8;   // 8 bf16 = 4 VGPRs
typedef __attribute__((ext_vector_type(4))) float f32x4;

__device__ __forceinline__ unsigned short f2bf(float f) {   // RNE fp32->bf16
    unsigned int u = __float_as_uint(f);
    return (unsigned short)((u + 0x7FFF + ((u >> 16) & 1)) >> 16);
}
__device__ __forceinline__ unsigned int pk2(float x, float y) {
    return (unsigned int)f2bf(x) | ((unsigned int)f2bf(y) << 16);
}
__device__ __forceinline__ short8 cvt8(float4 a, float4 b) {
    uint4 u = make_uint4(pk2(a.x, a.y), pk2(a.z, a.w), pk2(b.x, b.y), pk2(b.z, b.w));
    return *(short8*)&u;
}

// ---------------------------------------------------------------------------
// Single fused kernel. grid 256 = (b = bx&15, st = bx>>4), 512 thr.
//   Phase 1 (R5-verified k_yf body, looped over 16 K-chunks, double-buffered):
//     each block computes the FULL Y[b] = W @ X[b] privately, fp32 accum,
//     wave w owns o-rows [w*16, w*16+16).
//   Y -> YL in LDS, XOR-swizzled bf16 layout (same layout R8 verified).
//   Phase 2 (R8-verified k_out2 P3): out[b, st*128.., :] = X @ Y^T + bias,
//     B-frags conflict-free ds_read_b128 from YL.
// No workspace, no intermediate global traffic, no extra launches.
// ---------------------------------------------------------------------------
__global__ __launch_bounds__(512) void k_fused(const float* __restrict__ X,
                                               const float* __restrict__ W,
                                               const float* __restrict__ bias,
                                               float* __restrict__ out) {
    __shared__ unsigned short XT[2][64 * 132];   // 33.0 KB, double-buffered X chunk (transposed bf16)
    __shared__ unsigned short YL[YEL];           // 16 KB, swizzled bf16 Y[b]

    const int bx  = blockIdx.x;
    const int b   = bx & 15;     // same-b blocks contiguous mod 16 -> per-XCD L2 sees 2 batches
    const int st  = bx >> 4;
    const int tid = threadIdx.x;
    const int w   = tid >> 6;    // 0..7
    const int l   = tid & 63;
    const int n   = l & 15;
    const int q   = l >> 4;

    const float* Xb = X + (size_t)b * SS * DD;

    // ---- phase 1: Y[b] = W @ X[b], full K=2048, fp32 accumulators ----
    f32x4 acc[4];
#pragma unroll
    for (int j = 0; j < 4; ++j) acc[j] = {0.f, 0.f, 0.f, 0.f};

    // prologue: stage chunk 0 into XT[0]
    {
        float xr[16];
#pragma unroll
        for (int i = 0; i < 4; ++i) {
            const int tl = w * 4 + i * 32;
#pragma unroll
            for (int s = 0; s < 4; ++s)
                xr[i * 4 + s] = Xb[(size_t)(tl + s) * DD + l];
        }
#pragma unroll
        for (int i = 0; i < 4; ++i) {
            const int tl = w * 4 + i * 32;
            *(uint2*)&XT[0][l * 132 + tl] =
                make_uint2(pk2(xr[i * 4 + 0], xr[i * 4 + 1]),
                           pk2(xr[i * 4 + 2], xr[i * 4 + 3]));
        }
    }
    __syncthreads();

    const float* Wr = W + (size_t)(w * 16 + n) * SS;

#pragma unroll 2
    for (int ch = 0; ch < 16; ++ch) {
        const int buf = ch & 1;

        // T14 async-stage: issue next chunk's global loads BEFORE compute,
        // LDS-write them AFTER compute (latency hides under 16 MFMAs).
        float xr[16];
        if (ch < 15) {
            const float* Xc = Xb + (size_t)(ch + 1) * 128 * DD;
#pragma unroll
            for (int i = 0; i < 4; ++i) {
                const int tl = w * 4 + i * 32;
#pragma unroll
                for (int s = 0; s < 4; ++s)
                    xr[i * 4 + s] = Xc[(size_t)(tl + s) * DD + l];
            }
        }

        // compute chunk ch from XT[buf]  (R5-verified inner body)
        const float* Wc = Wr + ch * 128;
#pragma unroll
        for (int kk = 0; kk < 128; kk += 32) {
            const float4 wa = *(const float4*)(Wc + kk + q * 8);
            const float4 wb = *(const float4*)(Wc + kk + q * 8 + 4);
            const short8 a  = cvt8(wa, wb);
#pragma unroll
            for (int j = 0; j < 4; ++j) {
                const unsigned short* r = &XT[buf][(j * 16 + n) * 132 + kk + q * 8];
                const uint2 lo = *(const uint2*)(r);
                const uint2 hi = *(const uint2*)(r + 4);
                uint4 u = make_uint4(lo.x, lo.y, hi.x, hi.y);
                acc[j] = __builtin_amdgcn_mfma_f32_16x16x32_bf16(a, *(short8*)&u, acc[j], 0, 0, 0);
            }
        }

        if (ch < 15) {
#pragma unroll
            for (int i = 0; i < 4; ++i) {
                const int tl = w * 4 + i * 32;
                *(uint2*)&XT[buf ^ 1][l * 132 + tl] =
                    make_uint2(pk2(xr[i * 4 + 0], xr[i * 4 + 1]),
                               pk2(xr[i * 4 + 2], xr[i * 4 + 3]));
            }
        }
        __syncthreads();
    }

    // ---- Y -> YL (swizzled bf16; same store mapping R5/R8 verified) ----
#pragma unroll
    for (int j = 0; j < 4; ++j)
#pragma unroll
        for (int r = 0; r < 4; ++r) {
            const int o = w * 16 + q * 4 + r;
            const int d = j * 16 + n;
            YL[(o << 6) + ((((d >> 3) ^ (o & 7)) << 3) | (d & 7))] = f2bf(acc[j][r]);
        }
    __syncthreads();

    // ---- phase 2: out tile (R8-verified math, B-frags from YL) ----
    float bv[8];
#pragma unroll
    for (int j = 0; j < 8; ++j) bv[j] = bias[j * 16 + n];

    f32x4 oa[8];
#pragma unroll
    for (int j = 0; j < 8; ++j) oa[j] = {0.f, 0.f, 0.f, 0.f};

    const float* Xr = X + ((size_t)b * SS + st * 128 + w * 16 + n) * DD;
#pragma unroll
    for (int kk = 0; kk < DD; kk += 32) {
        const float4 xa = *(const float4*)(Xr + kk + q * 8);
        const float4 xb = *(const float4*)(Xr + kk + q * 8 + 4);
        const short8 a  = cvt8(xa, xb);
        const int c8    = (kk >> 3) + q;
#pragma unroll
        for (int j = 0; j < 8; ++j) {
            const int o = j * 16 + n;
            const uint4 u = *(const uint4*)&YL[(o << 6) + (((c8 ^ (o & 7)) << 3))];
            oa[j] = __builtin_amdgcn_mfma_f32_16x16x32_bf16(a, *(short8*)&u, oa[j], 0, 0, 0);
        }
    }

    float* op = out + ((size_t)b * SS + st * 128 + w * 16 + q * 4) * OO;
#pragma unroll
    for (int j = 0; j < 8; ++j)
#pragma unroll
        for (int r = 0; r < 4; ++r)
            op[(size_t)r * OO + j * 16 + n] = oa[j][r] + bv[j];
}

extern "C" void kernel_launch(void* const* d_in, const int* in_sizes, int n_in,
                              void* d_out, int out_size, void* d_ws, size_t ws_size,
                              hipStream_t stream) {
    const float* X    = (const float*)d_in[0];  // [B,S,D]
    const float* W    = (const float*)d_in[1];  // [OUT,S]
    const float* bias = (const float*)d_in[2];  // [OUT]
    float* out = (float*)d_out;                 // [B,S,OUT]

    k_fused<<<dim3(256), dim3(512), 0, stream>>>(X, W, bias, out);
}

// Round 3
// 114.555 us; speedup vs baseline: 1.0507x; 1.0507x over previous
//
#include <hip/hip_runtime.h>

#define BB 16
#define SS 2048
#define DD 64
#define OO 128
#define SPL 16
#define YEL (OO * DD)   // 8192 elems per Y[b] (and per slab)

#define MAGIC0 0x1B5C9A3Du
#define MAGIC1 0xE6A1507Bu

typedef __attribute__((ext_vector_type(8))) short short8;   // 8 bf16 = 4 VGPRs
typedef __attribute__((ext_vector_type(4))) float f32x4;

__device__ __forceinline__ unsigned short f2bf(float f) {   // RNE fp32->bf16
    unsigned int u = __float_as_uint(f);
    return (unsigned short)((u + 0x7FFF + ((u >> 16) & 1)) >> 16);
}
__device__ __forceinline__ unsigned int pk2(float x, float y) {
    return (unsigned int)f2bf(x) | ((unsigned int)f2bf(y) << 16);
}
__device__ __forceinline__ short8 cvt8(float4 a, float4 b) {
    uint4 u = make_uint4(pk2(a.x, a.y), pk2(a.z, a.w), pk2(b.x, b.y), pk2(b.z, b.w));
    return *(short8*)&u;
}
__device__ __forceinline__ float bflo(unsigned int u) { return __uint_as_float(u << 16); }
__device__ __forceinline__ float bfhi(unsigned int u) { return __uint_as_float(u & 0xffff0000u); }

// swizzled element index within a Y[b] / slab: o in [0,128), d in [0,64)
__device__ __forceinline__ int yswz(int o, int d) {
    return (o << 6) + ((((d >> 3) ^ (o & 7)) << 3) | (d & 7));
}

// ---------------------------------------------------------------------------
// Single launch, R0's exact work split (no compute replication):
//   block bx = (b = bx&15, p = bx>>4), 512 thr, grid 256 <= 256 CUs
//     (co-resident by construction -> flag handshake cannot deadlock).
//   phase 1 (R5-verified k_yf body): slab[b][p] = partial Y over its 128-t
//     K-slice, bf16, XOR-swizzled; publish with release + double-magic flags
//     (poison fill is a single repeated word -> can't alias BOTH magics;
//     missing re-poison is a benign same-value race: inputs identical/iter).
//   prefetch P3 A-frags + bias into regs (immune to the later cache inv).
//   spin on batch b's 16 flag pairs; acquire fence (inv stale L1/L2).
//   reduce 16 slabs -> YL (R8-verified stage), barrier,
//   P3 (R8-verified): out[b, p*128.., :] = X @ Y^T + bias.
// ---------------------------------------------------------------------------
__global__ __launch_bounds__(512) void k_all(const float* __restrict__ X,
                                             const float* __restrict__ W,
                                             const float* __restrict__ bias,
                                             float* __restrict__ out,
                                             unsigned short* __restrict__ YpB,
                                             unsigned int* flags) {
    __shared__ unsigned short XT[64 * 132];
    __shared__ unsigned short YL[YEL];   // 16KB, swizzled bf16 Y[b]

    const int bx  = blockIdx.x;
    const int b   = bx & 15;     // same-b blocks land on one XCD -> X[b] L2-local
    const int p   = bx >> 4;
    const int t0  = p * (SS / SPL);
    const int tid = threadIdx.x;
    const int w   = tid >> 6;
    const int l   = tid & 63;
    const int n   = l & 15;
    const int q   = l >> 4;

    // ---- phase 1: slab = W @ X[b]-slice (R5-verified body) ----
    const float* Xb = X + ((size_t)b * SS + t0) * DD;
#pragma unroll
    for (int i = 0; i < 4; ++i) {
        const int tl = w * 4 + i * 32;
        const float x0 = Xb[(size_t)(tl + 0) * DD + l];
        const float x1 = Xb[(size_t)(tl + 1) * DD + l];
        const float x2 = Xb[(size_t)(tl + 2) * DD + l];
        const float x3 = Xb[(size_t)(tl + 3) * DD + l];
        *(uint2*)&XT[l * 132 + tl] = make_uint2(pk2(x0, x1), pk2(x2, x3));
    }
    __syncthreads();

    f32x4 acc[4];
#pragma unroll
    for (int j = 0; j < 4; ++j) acc[j] = {0.f, 0.f, 0.f, 0.f};

    const float* Wr = W + (size_t)(w * 16 + n) * SS + t0;
#pragma unroll
    for (int kk = 0; kk < SS / SPL; kk += 32) {
        const float4 wa = *(const float4*)(Wr + kk + q * 8);
        const float4 wb = *(const float4*)(Wr + kk + q * 8 + 4);
        const short8 a  = cvt8(wa, wb);
#pragma unroll
        for (int j = 0; j < 4; ++j) {
            const unsigned short* r = &XT[(j * 16 + n) * 132 + kk + q * 8];
            const uint2 lo = *(const uint2*)(r);
            const uint2 hi = *(const uint2*)(r + 4);
            uint4 u = make_uint4(lo.x, lo.y, hi.x, hi.y);
            acc[j] = __builtin_amdgcn_mfma_f32_16x16x32_bf16(a, *(short8*)&u, acc[j], 0, 0, 0);
        }
    }

    unsigned short* slab = YpB + (size_t)(b * SPL + p) * YEL;
#pragma unroll
    for (int j = 0; j < 4; ++j)
#pragma unroll
        for (int r = 0; r < 4; ++r)
            slab[yswz(w * 16 + q * 4 + r, j * 16 + n)] = f2bf(acc[j][r]);

    __syncthreads();   // drains all waves' slab stores (vmcnt0 before barrier)

    if (tid < 2) {
        __threadfence();   // release: write back L2 -> LLC before publishing
        __hip_atomic_store(&flags[(b * SPL + p) * 2 + tid],
                           tid ? MAGIC1 : MAGIC0,
                           __ATOMIC_RELEASE, __HIP_MEMORY_SCOPE_AGENT);
    }

    // ---- prefetch P3 A-frags + bias into regs (slab-independent) ----
    short8 apre[2];
    const float* Xr = X + ((size_t)b * SS + p * 128 + w * 16 + n) * DD;
#pragma unroll
    for (int kk = 0; kk < DD; kk += 32) {
        const float4 xa = *(const float4*)(Xr + kk + q * 8);
        const float4 xb = *(const float4*)(Xr + kk + q * 8 + 4);
        apre[kk >> 5] = cvt8(xa, xb);
    }
    float bv[8];
#pragma unroll
    for (int j = 0; j < 8; ++j) bv[j] = bias[j * 16 + n];

    // ---- spin: wait for all 16 slabs of batch b (32 flag words) ----
    if (tid < 32) {
        unsigned int* f = &flags[(b * SPL + (tid >> 1)) * 2 + (tid & 1)];
        const unsigned int want = (tid & 1) ? MAGIC1 : MAGIC0;
        while (__hip_atomic_load(f, __ATOMIC_RELAXED, __HIP_MEMORY_SCOPE_AGENT) != want)
            __builtin_amdgcn_s_sleep(2);
    }
    __syncthreads();
    __threadfence();   // acquire: invalidate stale L1/L2 before reading slabs

    // ---- reduce 16 slabs -> YL (R8-verified stage, layout-preserving) ----
    const uint4* Yb4 = (const uint4*)(YpB + (size_t)b * SPL * YEL);
#pragma unroll
    for (int c = tid; c < YEL / 8; c += 512) {   // 2 chunks/thread
        float s[8];
#pragma unroll
        for (int e = 0; e < 8; ++e) s[e] = 0.f;
#pragma unroll
        for (int pp = 0; pp < SPL; ++pp) {
            const uint4 v = Yb4[(size_t)pp * (YEL / 8) + c];
            s[0] += bflo(v.x); s[1] += bfhi(v.x);
            s[2] += bflo(v.y); s[3] += bfhi(v.y);
            s[4] += bflo(v.z); s[5] += bfhi(v.z);
            s[6] += bflo(v.w); s[7] += bfhi(v.w);
        }
        ((uint4*)YL)[c] = make_uint4(pk2(s[0], s[1]), pk2(s[2], s[3]),
                                     pk2(s[4], s[5]), pk2(s[6], s[7]));
    }
    __syncthreads();

    // ---- P3: out tile (R8-verified math, A pre-staged in regs) ----
    f32x4 oa[8];
#pragma unroll
    for (int j = 0; j < 8; ++j) oa[j] = {0.f, 0.f, 0.f, 0.f};

#pragma unroll
    for (int kk = 0; kk < DD; kk += 32) {
        const short8 a = apre[kk >> 5];
        const int c8   = (kk >> 3) + q;
#pragma unroll
        for (int j = 0; j < 8; ++j) {
            const int o = j * 16 + n;
            const uint4 u = *(const uint4*)&YL[(o << 6) + (((c8 ^ (o & 7)) << 3))];
            oa[j] = __builtin_amdgcn_mfma_f32_16x16x32_bf16(a, *(short8*)&u, oa[j], 0, 0, 0);
        }
    }

    float* op = out + ((size_t)b * SS + p * 128 + w * 16 + q * 4) * OO;
#pragma unroll
    for (int j = 0; j < 8; ++j)
#pragma unroll
        for (int r = 0; r < 4; ++r)
            op[(size_t)r * OO + j * 16 + n] = oa[j][r] + bv[j];
}

extern "C" void kernel_launch(void* const* d_in, const int* in_sizes, int n_in,
                              void* d_out, int out_size, void* d_ws, size_t ws_size,
                              hipStream_t stream) {
    const float* X    = (const float*)d_in[0];  // [B,S,D]
    const float* W    = (const float*)d_in[1];  // [OUT,S]
    const float* bias = (const float*)d_in[2];  // [OUT]
    float* out = (float*)d_out;                 // [B,S,OUT]

    unsigned short* YpB  = (unsigned short*)d_ws;                       // 4.19MB bf16 slabs
    unsigned int*   flags = (unsigned int*)(YpB + (size_t)BB * SPL * YEL); // 2KB flag pairs

    k_all<<<dim3(256), dim3(512), 0, stream>>>(X, W, bias, out, YpB, flags);
}

// Round 4
// 81.979 us; speedup vs baseline: 1.4682x; 1.3974x over previous
//
#include <hip/hip_runtime.h>

#define BB 16
#define SS 2048
#define DD 64
#define OO 128
#define SPL 32
#define TSL (SS / SPL)  // 64 t-rows per slice
#define YEL (OO * DD)   // 8192 elems per Y[b] (and per slab)

typedef __attribute__((ext_vector_type(8))) short short8;   // 8 bf16 = 4 VGPRs
typedef __attribute__((ext_vector_type(4))) float f32x4;

__device__ __forceinline__ unsigned short f2bf(float f) {   // RNE fp32->bf16
    unsigned int u = __float_as_uint(f);
    return (unsigned short)((u + 0x7FFF + ((u >> 16) & 1)) >> 16);
}
__device__ __forceinline__ unsigned int pk2(float x, float y) {
    return (unsigned int)f2bf(x) | ((unsigned int)f2bf(y) << 16);
}
__device__ __forceinline__ short8 cvt8(float4 a, float4 b) {
    uint4 u = make_uint4(pk2(a.x, a.y), pk2(a.z, a.w), pk2(b.x, b.y), pk2(b.z, b.w));
    return *(short8*)&u;
}
__device__ __forceinline__ float bflo(unsigned int u) { return __uint_as_float(u << 16); }
__device__ __forceinline__ float bfhi(unsigned int u) { return __uint_as_float(u & 0xffff0000u); }

// swizzled element index within a Y[b] / slab: o in [0,128), d in [0,64)
__device__ __forceinline__ int yswz(int o, int d) {
    return (o << 6) + ((((d >> 3) ^ (o & 7)) << 3) | (d & 7));
}

// ---------------------------------------------------------------------------
// k_yf (R5-verified body, SPL=32): slab[b][p] = partial Y over a 64-t slice.
// grid 512 = (b = bx&15, p = bx>>4) -> 2 blocks/CU, 16 waves/CU (vs 8 in R0):
// doubles latency-hiding for the cold X/W streams; two independent barrier
// domains per CU so one block computes while the other stages.
// ---------------------------------------------------------------------------
__global__ __launch_bounds__(512) void k_yf(const float* __restrict__ X,
                                            const float* __restrict__ W,
                                            unsigned short* __restrict__ YpB) {
    __shared__ unsigned short XT[64 * 132];   // [d][t] bf16, only t<64 used (16.9KB)

    const int bx  = blockIdx.x;
    const int b   = bx & 15;
    const int p   = bx >> 4;          // 0..31
    const int t0  = p * TSL;
    const int tid = threadIdx.x;
    const int w   = tid >> 6;
    const int l   = tid & 63;

    const float* Xb = X + ((size_t)b * SS + t0) * DD;
#pragma unroll
    for (int i = 0; i < 2; ++i) {     // t-rows 0..63 of this slice
        const int tl = w * 4 + i * 32;
        const float x0 = Xb[(size_t)(tl + 0) * DD + l];
        const float x1 = Xb[(size_t)(tl + 1) * DD + l];
        const float x2 = Xb[(size_t)(tl + 2) * DD + l];
        const float x3 = Xb[(size_t)(tl + 3) * DD + l];
        *(uint2*)&XT[l * 132 + tl] = make_uint2(pk2(x0, x1), pk2(x2, x3));
    }
    __syncthreads();

    const int n = l & 15;
    const int q = l >> 4;

    f32x4 acc[4];
#pragma unroll
    for (int j = 0; j < 4; ++j) acc[j] = {0.f, 0.f, 0.f, 0.f};

    const float* Wr = W + (size_t)(w * 16 + n) * SS + t0;
#pragma unroll
    for (int kk = 0; kk < TSL; kk += 32) {    // 2 iters
        const float4 wa = *(const float4*)(Wr + kk + q * 8);
        const float4 wb = *(const float4*)(Wr + kk + q * 8 + 4);
        const short8 a  = cvt8(wa, wb);
#pragma unroll
        for (int j = 0; j < 4; ++j) {
            const unsigned short* r = &XT[(j * 16 + n) * 132 + kk + q * 8];
            const uint2 lo = *(const uint2*)(r);
            const uint2 hi = *(const uint2*)(r + 4);
            uint4 u = make_uint4(lo.x, lo.y, hi.x, hi.y);
            acc[j] = __builtin_amdgcn_mfma_f32_16x16x32_bf16(a, *(short8*)&u, acc[j], 0, 0, 0);
        }
    }

    unsigned short* slab = YpB + (size_t)(b * SPL + p) * YEL;
#pragma unroll
    for (int j = 0; j < 4; ++j)
#pragma unroll
        for (int r = 0; r < 4; ++r)
            slab[yswz(w * 16 + q * 4 + r, j * 16 + n)] = f2bf(acc[j][r]);
}

// ---------------------------------------------------------------------------
// k_out2 (R8-verified math): per-block reduction of the 32 bf16 slabs -> YL
// (swizzled LDS), then out[b, st*128.., :] = X @ Y^T + bias. P3 A-frags and
// bias are prefetched into registers BEFORE the reduce (R3-proven) so their
// global latency hides under the reduce instead of serializing after the
// barrier. grid 256 = (b = bx&15, st = bx>>4), 512 thr.
// ---------------------------------------------------------------------------
__global__ __launch_bounds__(512) void k_out2(const float* __restrict__ X,
                                              const unsigned short* __restrict__ YpB,
                                              const float* __restrict__ bias,
                                              float* __restrict__ out) {
    __shared__ unsigned short YL[YEL];   // 16KB, swizzled bf16 Y[b]

    const int bx  = blockIdx.x;
    const int b   = bx & 15;
    const int st  = bx >> 4;
    const int tid = threadIdx.x;
    const int w   = tid >> 6;
    const int l   = tid & 63;
    const int n   = l & 15;
    const int q   = l >> 4;

    // ---- prefetch P3 A-frags + bias into regs (YL-independent) ----
    short8 apre[2];
    const float* Xr = X + ((size_t)b * SS + st * 128 + w * 16 + n) * DD;
#pragma unroll
    for (int kk = 0; kk < DD; kk += 32) {
        const float4 xa = *(const float4*)(Xr + kk + q * 8);
        const float4 xb = *(const float4*)(Xr + kk + q * 8 + 4);
        apre[kk >> 5] = cvt8(xa, xb);
    }
    float bv[8];
#pragma unroll
    for (int j = 0; j < 8; ++j) bv[j] = bias[j * 16 + n];

    // ---- stage: reduce 32 slabs elementwise (coalesced uint4 chunks) ----
    const uint4* Yb4 = (const uint4*)(YpB + (size_t)b * SPL * YEL);
#pragma unroll
    for (int c = tid; c < YEL / 8; c += 512) {   // 2 chunks/thread
        float s[8];
#pragma unroll
        for (int e = 0; e < 8; ++e) s[e] = 0.f;
#pragma unroll
        for (int pp = 0; pp < SPL; ++pp) {
            const uint4 v = Yb4[(size_t)pp * (YEL / 8) + c];
            s[0] += bflo(v.x); s[1] += bfhi(v.x);
            s[2] += bflo(v.y); s[3] += bfhi(v.y);
            s[4] += bflo(v.z); s[5] += bfhi(v.z);
            s[6] += bflo(v.w); s[7] += bfhi(v.w);
        }
        ((uint4*)YL)[c] = make_uint4(pk2(s[0], s[1]), pk2(s[2], s[3]),
                                     pk2(s[4], s[5]), pk2(s[6], s[7]));
    }

    f32x4 acc[8];
#pragma unroll
    for (int j = 0; j < 8; ++j) acc[j] = {0.f, 0.f, 0.f, 0.f};

    __syncthreads();

    // ---- P3: out tile (R8-verified math, A pre-staged in regs) ----
#pragma unroll
    for (int kk = 0; kk < DD; kk += 32) {
        const short8 a = apre[kk >> 5];
        const int c8   = (kk >> 3) + q;
#pragma unroll
        for (int j = 0; j < 8; ++j) {
            const int o = j * 16 + n;
            const uint4 u = *(const uint4*)&YL[(o << 6) + (((c8 ^ (o & 7)) << 3))];
            acc[j] = __builtin_amdgcn_mfma_f32_16x16x32_bf16(a, *(short8*)&u, acc[j], 0, 0, 0);
        }
    }

    float* op = out + ((size_t)b * SS + st * 128 + w * 16 + q * 4) * OO;
#pragma unroll
    for (int j = 0; j < 8; ++j)
#pragma unroll
        for (int r = 0; r < 4; ++r)
            op[(size_t)r * OO + j * 16 + n] = acc[j][r] + bv[j];
}

extern "C" void kernel_launch(void* const* d_in, const int* in_sizes, int n_in,
                              void* d_out, int out_size, void* d_ws, size_t ws_size,
                              hipStream_t stream) {
    const float* X    = (const float*)d_in[0];  // [B,S,D]
    const float* W    = (const float*)d_in[1];  // [OUT,S]
    const float* bias = (const float*)d_in[2];  // [OUT]
    float* out = (float*)d_out;                 // [B,S,OUT]

    unsigned short* YpB = (unsigned short*)d_ws;   // [B*SPL][YEL] bf16 slabs, 8.4MB

    k_yf <<<dim3(512), dim3(512), 0, stream>>>(X, W, YpB);
    k_out2<<<dim3(256), dim3(512), 0, stream>>>(X, YpB, bias, out);
}